// Round 13
// baseline (82.402 us; speedup 1.0000x reference)
//
#include <hip/hip_runtime.h>
#include <hip/hip_bf16.h>

// Problem constants
constexpr int R  = 59;
constexpr int D  = 128;
constexpr int NK = 16;      // neighbors per (r,n)
constexpr int N  = 1024;
constexpr int T  = 32;
constexpr int F  = 10;
constexpr int H4 = 512;     // 4*D
constexpr int WSTRIDE = 2*D + R; // 315

typedef __attribute__((ext_vector_type(8))) short short8;   // 8 bf16 (4 VGPR)
typedef __attribute__((ext_vector_type(4))) float f32x4;    // MFMA C/D

__device__ __forceinline__ float sigm(float x) {
  return __builtin_amdgcn_rcpf(1.0f + __expf(-x));
}
__device__ __forceinline__ float tanh_(float x) {
  return 2.0f * __builtin_amdgcn_rcpf(1.0f + __expf(-2.0f * x)) - 1.0f;
}
__device__ __forceinline__ ushort f2bf(float f) {          // RNE fp32->bf16
  unsigned u = __float_as_uint(f);
  u += 0x7FFF + ((u >> 16) & 1);
  return (ushort)(u >> 16);
}
__device__ __forceinline__ float bf2f(ushort u) {
  return __uint_as_float(((unsigned)u) << 16);
}

// ---------------------------------------------------------------------------
// Runtime dtype detection (proven round 2). Computed once in convert_kernel.
// ---------------------------------------------------------------------------
__device__ int g_detect_f32(const void* windows) {
  const __hip_bfloat16* p = (const __hip_bfloat16*)windows;
  int weird = 0;
  for (int i = 0; i < 128; ++i) {
    float v = __bfloat162float(p[i]);
    float a = fabsf(v);
    if (!(a <= 100.0f) || (v != 0.0f && a < 1e-8f)) ++weird;
  }
  return weird > 8;
}

__device__ __forceinline__ float rdsrc(const void* p, int i, int isf32) {
  return isf32 ? ((const float*)p)[i]
               : __bfloat162float(((const __hip_bfloat16*)p)[i]);
}

struct CvtA {
  const void* small[6];   // W_state, b_state, W_relattn, b_relattn, W_pred, b_pred
  int soff[7];            // prefix sums, soff[6] = 19347
  const void* win;        // windows [1024][32][10]
  const void* wk;         // [10][512]
  const void* wr;         // [128][512]
  const void* bias;       // [512]
};

// Converts small (attn) tensors to fp32, packs Wt for proj, packs LSTM
// B-fragments (bf16, per-lane order, bias baked at k=10).  (r9 version.)
__global__ __launch_bounds__(256) void convert_kernel(
    CvtA a, float* __restrict__ csm, float* __restrict__ wt,
    ushort* __restrict__ bpk, int* __restrict__ flag_out)
{
  __shared__ int sflag;
  if (threadIdx.x == 0) sflag = g_detect_f32(a.win);
  __syncthreads();
  const int isf32 = sflag;
  if (blockIdx.x == 0 && threadIdx.x == 0) flag_out[0] = isf32;
  const int gid = blockIdx.x * 256 + threadIdx.x;
  const int stride = gridDim.x * 256;

  // 1) small attn tensors -> fp32
  for (int i = gid; i < a.soff[6]; i += stride) {
    int t = 0;
    while (t < 5 && i >= a.soff[t + 1]) ++t;
    csm[i] = rdsrc(a.small[t], i - a.soff[t], isf32);
  }
  // 2) Wt pack for proj: 128x128, j: 59 Wn | 59 Wc | wc | zero
  for (int i = gid; i < 128 * 128; i += stride) {
    const int d = i >> 7, j = i & 127;
    float v = 0.0f;
    if (j < 59)        v = rdsrc(a.small[0], j * WSTRIDE + D + d, isf32);
    else if (j < 118)  v = rdsrc(a.small[0], (j - 59) * WSTRIDE + d, isf32);
    else if (j == 118) v = rdsrc(a.small[2], d, isf32);
    wt[i] = v;
  }
  // 3) LSTM B fragments: bpk[(((w*4+g)*5+kf)*64+l)*8 + j]
  for (int fi = gid; fi < 10240; fi += stride) {
    const int l  = fi & 63;
    const int kf = (fi >> 6) % 5;
    const int g  = ((fi >> 6) / 5) & 3;
    const int w  = (fi >> 6) / 20;
    const int col = g * 128 + w * 16 + (l & 15);
    const int q   = l >> 4;
#pragma unroll
    for (int j = 0; j < 8; ++j) {
      const int k = q * 8 + j;
      float v;
      if (kf < 4)      v = rdsrc(a.wr, (kf * 32 + k) * H4 + col, isf32);
      else if (k < 10) v = rdsrc(a.wk, k * H4 + col, isf32);
      else if (k == 10) v = rdsrc(a.bias, col, isf32);
      else             v = 0.0f;
      bpk[fi * 8 + j] = f2bf(v);
    }
  }
}

// ---------------------------------------------------------------------------
// Kernel 1: MFMA LSTM (r9 loop, byte-identical) + FUSED PROJ EPILOGUE.
// Each block owns feats rows n0+1..n0+16 completely, so after the T-loop it
// computes their projections in-block: fp32 h staged into the dead xfrag LDS
// (stride 132, broadcast reads), 512 threads x (16 samples x 119 outputs),
// coalesced wt reads. Removes the proj_kernel launch + gap entirely.
// ---------------------------------------------------------------------------
__global__ __launch_bounds__(512)
__attribute__((amdgpu_waves_per_eu(2, 2)))
void lstm_kernel(const ushort* __restrict__ bpk, const void* __restrict__ win_raw,
                 const int* __restrict__ flagp,
                 float* __restrict__ feats, ushort* __restrict__ fb16,
                 const float* __restrict__ wt,
                 float* __restrict__ cur_term, float* __restrict__ nbr_proj,
                 float* __restrict__ curwc)
{
  const int tid = threadIdx.x;
  const int w   = tid >> 6;    // wave 0..7
  const int l   = tid & 63;    // lane
  const int n0  = blockIdx.x * 16;

  __shared__ ushort hbuf[2][16 * 136];     // bf16 h[sample][d], dbuf, padded
  __shared__ ushort xfrag[T * 64 * 8];     // x A-frags (32 KB); reused as fp32 h in epilogue

  if (blockIdx.x == 0) {
    if (tid < D) { feats[tid] = 0.0f; fb16[tid] = 0; }
    if (tid < R) nbr_proj[tid] = 0.0f;     // feats row 0 is zero -> proj = 0
  }

  const int isf32 = flagp[0];
  // Prebuild per-t x A-fragments from raw windows.
  for (int p = tid; p < T * 64; p += 512) {
    const int t = p >> 6, ll = p & 63, s = ll & 15, q = ll >> 4;
    short8 pk;
#pragma unroll
    for (int j = 0; j < 8; ++j) {
      const int f = q * 8 + j;
      float v = (f < F) ? rdsrc(win_raw, (n0 + s) * (T * F) + t * F + f, isf32)
                        : (f == 10 ? 1.0f : 0.0f);
      pk[j] = (short)f2bf(v);
    }
    *(short8*)&xfrag[p * 8] = pk;
  }
  for (int i = tid; i < 2 * 16 * 136; i += 512) ((ushort*)hbuf)[i] = 0;

  // Persistent B fragments: coalesced 16B loads from bpk.
  short8 B[4][5];
#pragma unroll
  for (int g = 0; g < 4; ++g)
#pragma unroll
    for (int kf = 0; kf < 5; ++kf)
      B[g][kf] = *(const short8*)&bpk[((((w * 4 + g) * 5 + kf) * 64) + l) * 8];

  f32x4 c4 = {0.f, 0.f, 0.f, 0.f};
  float hreg[4];
  const int lq    = l >> 4;
  const int krow0 = lq * 8;
  const int srow0 = lq * 4;                // sample row base (C layout)
  const int col_d = w * 16 + (l & 15);     // this lane's d col

  __syncthreads();

  for (int t = 0; t < T; ++t) {
    const ushort* hb = hbuf[t & 1];
    short8 A[5];
#pragma unroll
    for (int kf = 0; kf < 4; ++kf)
      A[kf] = *(const short8*)(hb + (l & 15) * 136 + kf * 32 + krow0);
    A[4] = *(const short8*)(xfrag + (t * 64 + l) * 8);

    f32x4 acc[4];
#pragma unroll
    for (int g = 0; g < 4; ++g) {
      acc[g] = (f32x4){0.f, 0.f, 0.f, 0.f};
#pragma unroll
      for (int kf = 0; kf < 5; ++kf)
        acc[g] = __builtin_amdgcn_mfma_f32_16x16x32_bf16(A[kf], B[g][kf], acc[g], 0, 0, 0);
    }

    ushort* hw = hbuf[(t + 1) & 1];
#pragma unroll
    for (int r = 0; r < 4; ++r) {
      const float i_ = sigm(acc[0][r]);
      const float f_ = sigm(acc[1][r]);
      const float g_ = tanh_(acc[2][r]);
      const float o_ = sigm(acc[3][r]);
      c4[r]   = f_ * c4[r] + i_ * g_;
      hreg[r] = o_ * tanh_(c4[r]);
      hw[(srow0 + r) * 136 + col_d] = f2bf(hreg[r]);
    }
    __syncthreads();
  }

  // ---- global h writes + stage fp32 h into LDS for the fused proj ----
  float* hf32 = (float*)xfrag;             // 16*132 floats = 8.25 KB (xfrag dead)
#pragma unroll
  for (int r = 0; r < 4; ++r) {
    feats[(n0 + srow0 + r + 1) * D + col_d] = hreg[r];
    fb16 [(n0 + srow0 + r + 1) * D + col_d] = f2bf(hreg[r]);
    hf32[(srow0 + r) * 132 + col_d] = hreg[r];
  }
  __syncthreads();

  // ---- fused proj: 16 samples x 119 outputs, coalesced wt reads ----
  for (int p = tid; p < 16 * 120; p += 512) {
    const int s = p / 120;
    const int j = p % 120;
    if (j >= 119) continue;
    const float* hrow = &hf32[s * 132];
    float acc = 0.0f;
#pragma unroll 8
    for (int d = 0; d < 128; ++d)
      acc = fmaf(hrow[d], wt[d * 128 + j], acc);
    const int m = n0 + s;                  // cur index (feats row m+1)
    if (j < 59)       nbr_proj[(m + 1) * R + j] = acc;
    else if (j < 118) cur_term[m * R + (j - 59)] = acc;
    else              curwc[m] = acc;
  }
}

// ---------------------------------------------------------------------------
// Kernel 3: fused attention (exact r9 version — best measured).
// ---------------------------------------------------------------------------
__device__ __forceinline__ void store_out(void* out, int i, float v, int outf32) {
  if (outf32) ((float*)out)[i] = v;
  else        ((__hip_bfloat16*)out)[i] = __float2bfloat16(v);
}

__global__ __launch_bounds__(256) void attn_kernel(
    const float* __restrict__ feats, const ushort* __restrict__ fb16,
    const int* __restrict__ neighbors,
    const float* __restrict__ W_state, const float* __restrict__ b_state,
    const float* __restrict__ W_relattn, const float* __restrict__ b_relattn,
    const float* __restrict__ W_pred, const float* __restrict__ b_pred,
    const float* __restrict__ cur_term, const float* __restrict__ nbr_proj,
    const float* __restrict__ curwc, const int* __restrict__ flagp,
    void* __restrict__ out)
{
  const int n   = blockIdx.x;
  const int tid = threadIdx.x;

  __shared__ ushort rr[R * 136];      // rel_reps bf16, 16B-aligned rows
  __shared__ int    idx_lds[R * NK];
  __shared__ float  w_lds[NK * 60];   // transposed [k][r]
  __shared__ float  s2part[16 * 68];  // D1 partial dots [d8][r], bank-defused
  __shared__ float  wn_lds[D];
  __shared__ float  ct_lds[R];
  __shared__ float  rt_lds[R];
  __shared__ float  s2_lds[R];
  __shared__ float  aw_lds[R];
  __shared__ float  upd_lds[D];
  __shared__ int    sflag;

  // A: constants + neighbor indices
  if (tid == 0) sflag = flagp[0];
  if (tid < R) {
    ct_lds[tid] = cur_term[n * R + tid];
    rt_lds[tid] = W_state[tid * WSTRIDE + 2 * D + tid] + b_state[tid];
  }
  if (tid >= 128 && tid < 256) wn_lds[tid - 128] = W_relattn[D + (tid - 128)];
  for (int i = tid; i < R * NK; i += 256) {
    const int r = i >> 4, k = i & 15;
    idx_lds[i] = neighbors[(r * N + n) * NK + k];
  }
  __syncthreads();
  const int outf32 = sflag;

  // B1: scores -> w_lds[k][r] (relu'd)
  for (int i = tid; i < R * NK; i += 256) {
    const int r = i >> 4, k = i & 15;
    float s = ct_lds[r] + nbr_proj[idx_lds[i] * R + r] + rt_lds[r];
    w_lds[k * 60 + r] = fmaxf(s, 0.0f);
  }
  __syncthreads();

  // B2: softmax over K per r (conflict-free columns)
  if (tid < R) {
    float mx = 0.0f;
#pragma unroll
    for (int k = 0; k < NK; ++k) mx = fmaxf(mx, w_lds[k * 60 + tid]);
    float sum = 0.0f;
    float e[NK];
#pragma unroll
    for (int k = 0; k < NK; ++k) {
      e[k] = __expf(w_lds[k * 60 + tid] - mx);
      sum += e[k];
    }
    const float inv = __builtin_amdgcn_rcpf(sum);
#pragma unroll
    for (int k = 0; k < NK; ++k) w_lds[k * 60 + tid] = e[k] * inv;
  }
  __syncthreads();

  // C: bf16 gather, fp32 accumulate; fold D1 partial dot; bf16 rr store.
  {
    const int d8 = tid & 15;        // 8-elem chunk of d
    const int rp = tid >> 4;        // 16 parallel r slots
    for (int r = rp; r < R; r += 16) {
      float acc[8];
#pragma unroll
      for (int j = 0; j < 8; ++j) acc[j] = 0.0f;
#pragma unroll
      for (int k = 0; k < NK; ++k) {
        const int m = idx_lds[r * NK + k];
        const uint4 v = *(const uint4*)&fb16[m * D + d8 * 8];
        const float wv = w_lds[k * 60 + r];
        acc[0] = fmaf(wv, __uint_as_float(v.x << 16),          acc[0]);
        acc[1] = fmaf(wv, __uint_as_float(v.x & 0xffff0000u),  acc[1]);
        acc[2] = fmaf(wv, __uint_as_float(v.y << 16),          acc[2]);
        acc[3] = fmaf(wv, __uint_as_float(v.y & 0xffff0000u),  acc[3]);
        acc[4] = fmaf(wv, __uint_as_float(v.z << 16),          acc[4]);
        acc[5] = fmaf(wv, __uint_as_float(v.z & 0xffff0000u),  acc[5]);
        acc[6] = fmaf(wv, __uint_as_float(v.w << 16),          acc[6]);
        acc[7] = fmaf(wv, __uint_as_float(v.w & 0xffff0000u),  acc[7]);
      }
      short8 pk;
#pragma unroll
      for (int j = 0; j < 8; ++j) pk[j] = (short)f2bf(acc[j]);
      *(short8*)&rr[r * 136 + d8 * 8] = pk;
      float p = 0.0f;
#pragma unroll
      for (int j = 0; j < 8; ++j) p = fmaf(acc[j], wn_lds[d8 * 8 + j], p);
      s2part[d8 * 68 + r] = p;
    }
  }
  __syncthreads();

  // D1: s2[r] = relu(curwc + sum of partials + wr[r] + b) — no shuffles
  if (tid < R) {
    float dot = 0.0f;
#pragma unroll
    for (int q = 0; q < 16; ++q) dot += s2part[q * 68 + tid];
    float v = curwc[n] + dot + W_relattn[2 * D + tid] + b_relattn[0];
    s2_lds[tid] = fmaxf(v, 0.0f);
  }
  __syncthreads();

  // D2: softmax over r (wave 0)
  if (tid < 64) {
    float v = (tid < R) ? s2_lds[tid] : -1e30f;
    float mx = v;
    for (int off = 32; off; off >>= 1) mx = fmaxf(mx, __shfl_xor(mx, off));
    float e = (tid < R) ? __expf(v - mx) : 0.0f;
    float sum = e;
    for (int off = 32; off; off >>= 1) sum += __shfl_xor(sum, off);
    if (tid < R) aw_lds[tid] = e / sum;
  }
  __syncthreads();

  // E: rel_agg + updated (rr bf16 unpack)
  if (tid < D) {
    float agg = 0.0f;
    for (int r = 0; r < R; ++r) agg = fmaf(aw_lds[r], bf2f(rr[r * 136 + tid]), agg);
    const float upd = feats[(n + 1) * D + tid] + agg;
    store_out(out, 2 * 3 * N + n * D + tid, upd, outf32);
    upd_lds[tid] = upd;
  }
  __syncthreads();

  // F: logits + prediction softmax (wave 0)
  if (tid < 64) {
    float p[3];
#pragma unroll
    for (int j = 0; j < 3; ++j) {
      float v = upd_lds[tid] * W_pred[tid * 3 + j] +
                upd_lds[tid + 64] * W_pred[(tid + 64) * 3 + j];
      for (int off = 32; off; off >>= 1) v += __shfl_xor(v, off);
      p[j] = v + b_pred[j];
    }
    if (tid == 0) {
      const float mx = fmaxf(p[0], fmaxf(p[1], p[2]));
      const float e0 = __expf(p[0] - mx), e1 = __expf(p[1] - mx), e2 = __expf(p[2] - mx);
      const float s = e0 + e1 + e2;
      store_out(out, n * 3 + 0, p[0], outf32);
      store_out(out, n * 3 + 1, p[1], outf32);
      store_out(out, n * 3 + 2, p[2], outf32);
      store_out(out, 3 * N + n * 3 + 0, e0 / s, outf32);
      store_out(out, 3 * N + n * 3 + 1, e1 / s, outf32);
      store_out(out, 3 * N + n * 3 + 2, e2 / s, outf32);
    }
  }
}

// ---------------------------------------------------------------------------
extern "C" void kernel_launch(void* const* d_in, const int* in_sizes, int n_in,
                              void* d_out, int out_size, void* d_ws, size_t ws_size,
                              hipStream_t stream)
{
  const int* neighbors = (const int*)d_in[1];
  float* ws = (float*)d_ws;

  CvtA ca;
  {
    constexpr int SS[6] = {18585, 59, 315, 1, 384, 3};
    int off = 0;
    for (int i = 0; i < 6; ++i) { ca.small[i] = d_in[5 + i]; ca.soff[i] = off; off += SS[i]; }
    ca.soff[6] = off;   // 19347
    ca.win  = d_in[0];
    ca.wk   = d_in[2];
    ca.wr   = d_in[3];
    ca.bias = d_in[4];
  }

  float*  csm      = ws;                         // 19360 (19347 + pad)
  float*  wtpack   = csm + 19360;                // 16384
  float*  feats    = wtpack + 16384;             // 131200
  float*  cur_term = feats + 131200;             // 60416
  float*  nbr_proj = cur_term + 60416;           // 60480
  float*  curwc    = nbr_proj + 60480;           // 1024
  int*    flagp    = (int*)(curwc + 1024);       // 16 floats pad
  ushort* bpk      = (ushort*)(curwc + 1040);    // 81920 ushort
  ushort* fb16     = bpk + 81920;                // 131200 ushort

  const float* c_Wstate = csm;
  const float* c_bstate = csm + 18585;
  const float* c_Wrel   = csm + 18644;
  const float* c_brel   = csm + 18959;
  const float* c_Wpred  = csm + 18960;
  const float* c_bpred  = csm + 19344;

  convert_kernel<<<256, 256, 0, stream>>>(ca, csm, wtpack, bpk, flagp);
  lstm_kernel<<<N / 16, 512, 0, stream>>>(bpk, d_in[0], flagp, feats, fb16,
                                          wtpack, cur_term, nbr_proj, curwc);
  attn_kernel<<<N, 256, 0, stream>>>(feats, fb16, neighbors, c_Wstate, c_bstate, c_Wrel,
                                     c_brel, c_Wpred, c_bpred,
                                     cur_term, nbr_proj, curwc, flagp, d_out);
}

// Round 14
// 75.187 us; speedup vs baseline: 1.0960x; 1.0960x over previous
//
#include <hip/hip_runtime.h>
#include <hip/hip_bf16.h>

// Problem constants
constexpr int R  = 59;
constexpr int D  = 128;
constexpr int NK = 16;      // neighbors per (r,n)
constexpr int N  = 1024;
constexpr int T  = 32;
constexpr int F  = 10;
constexpr int H4 = 512;     // 4*D
constexpr int WSTRIDE = 2*D + R; // 315

typedef __attribute__((ext_vector_type(8))) short short8;   // 8 bf16 (4 VGPR)
typedef __attribute__((ext_vector_type(4))) float f32x4;    // MFMA C/D

__device__ __forceinline__ float sigm(float x) {
  return __builtin_amdgcn_rcpf(1.0f + __expf(-x));
}
__device__ __forceinline__ float tanh_(float x) {
  return 2.0f * __builtin_amdgcn_rcpf(1.0f + __expf(-2.0f * x)) - 1.0f;
}
__device__ __forceinline__ ushort f2bf(float f) {          // RNE fp32->bf16
  unsigned u = __float_as_uint(f);
  u += 0x7FFF + ((u >> 16) & 1);
  return (ushort)(u >> 16);
}
__device__ __forceinline__ float bf2f(ushort u) {
  return __uint_as_float(((unsigned)u) << 16);
}

// ---------------------------------------------------------------------------
// Runtime dtype detection (proven round 2). Computed once in convert_kernel.
// ---------------------------------------------------------------------------
__device__ int g_detect_f32(const void* windows) {
  const __hip_bfloat16* p = (const __hip_bfloat16*)windows;
  int weird = 0;
  for (int i = 0; i < 128; ++i) {
    float v = __bfloat162float(p[i]);
    float a = fabsf(v);
    if (!(a <= 100.0f) || (v != 0.0f && a < 1e-8f)) ++weird;
  }
  return weird > 8;
}

__device__ __forceinline__ float rdsrc(const void* p, int i, int isf32) {
  return isf32 ? ((const float*)p)[i]
               : __bfloat162float(((const __hip_bfloat16*)p)[i]);
}

struct CvtA {
  const void* small[6];   // W_state, b_state, W_relattn, b_relattn, W_pred, b_pred
  int soff[7];            // prefix sums, soff[6] = 19347
  const void* win;        // windows [1024][32][10]
  const void* wk;         // [10][512]
  const void* wr;         // [128][512]
  const void* bias;       // [512]
};

// Converts small (attn) tensors to fp32, packs Wt for proj, packs LSTM
// B-fragments (bf16, per-lane order, bias baked at k=10).  (r9 version.)
__global__ __launch_bounds__(256) void convert_kernel(
    CvtA a, float* __restrict__ csm, float* __restrict__ wt,
    ushort* __restrict__ bpk, int* __restrict__ flag_out)
{
  __shared__ int sflag;
  if (threadIdx.x == 0) sflag = g_detect_f32(a.win);
  __syncthreads();
  const int isf32 = sflag;
  if (blockIdx.x == 0 && threadIdx.x == 0) flag_out[0] = isf32;
  const int gid = blockIdx.x * 256 + threadIdx.x;
  const int stride = gridDim.x * 256;

  // 1) small attn tensors -> fp32
  for (int i = gid; i < a.soff[6]; i += stride) {
    int t = 0;
    while (t < 5 && i >= a.soff[t + 1]) ++t;
    csm[i] = rdsrc(a.small[t], i - a.soff[t], isf32);
  }
  // 2) Wt pack for proj: 128x128, j: 59 Wn | 59 Wc | wc | zero
  for (int i = gid; i < 128 * 128; i += stride) {
    const int d = i >> 7, j = i & 127;
    float v = 0.0f;
    if (j < 59)        v = rdsrc(a.small[0], j * WSTRIDE + D + d, isf32);
    else if (j < 118)  v = rdsrc(a.small[0], (j - 59) * WSTRIDE + d, isf32);
    else if (j == 118) v = rdsrc(a.small[2], d, isf32);
    wt[i] = v;
  }
  // 3) LSTM B fragments: bpk[(((w*4+g)*5+kf)*64+l)*8 + j]
  for (int fi = gid; fi < 10240; fi += stride) {
    const int l  = fi & 63;
    const int kf = (fi >> 6) % 5;
    const int g  = ((fi >> 6) / 5) & 3;
    const int w  = (fi >> 6) / 20;
    const int col = g * 128 + w * 16 + (l & 15);
    const int q   = l >> 4;
#pragma unroll
    for (int j = 0; j < 8; ++j) {
      const int k = q * 8 + j;
      float v;
      if (kf < 4)      v = rdsrc(a.wr, (kf * 32 + k) * H4 + col, isf32);
      else if (k < 10) v = rdsrc(a.wk, k * H4 + col, isf32);
      else if (k == 10) v = rdsrc(a.bias, col, isf32);
      else             v = 0.0f;
      bpk[fi * 8 + j] = f2bf(v);
    }
  }
}

// ---------------------------------------------------------------------------
// Kernel 1: MFMA LSTM (r9 exact — best measured). 64 blocks x 16 samples,
// 8 waves (2/SIMD). Wave w owns cols [16w,16w+16) of each gate; persistent
// B fragments; one barrier per step.
// ---------------------------------------------------------------------------
__global__ __launch_bounds__(512)
__attribute__((amdgpu_waves_per_eu(2, 2)))
void lstm_kernel(const ushort* __restrict__ bpk, const void* __restrict__ win_raw,
                 const int* __restrict__ flagp,
                 float* __restrict__ feats, ushort* __restrict__ fb16)
{
  const int tid = threadIdx.x;
  const int w   = tid >> 6;    // wave 0..7
  const int l   = tid & 63;    // lane
  const int n0  = blockIdx.x * 16;

  __shared__ ushort hbuf[2][16 * 136];     // bf16 h[sample][d], dbuf, padded
  __shared__ ushort xfrag[T * 64 * 8];     // prebuilt A-frags for x (32 KB)

  if (blockIdx.x == 0 && tid < D) { feats[tid] = 0.0f; fb16[tid] = 0; }

  const int isf32 = flagp[0];
  // Prebuild per-t x A-fragments from raw windows.
  for (int p = tid; p < T * 64; p += 512) {
    const int t = p >> 6, ll = p & 63, s = ll & 15, q = ll >> 4;
    short8 pk;
#pragma unroll
    for (int j = 0; j < 8; ++j) {
      const int f = q * 8 + j;
      float v = (f < F) ? rdsrc(win_raw, (n0 + s) * (T * F) + t * F + f, isf32)
                        : (f == 10 ? 1.0f : 0.0f);
      pk[j] = (short)f2bf(v);
    }
    *(short8*)&xfrag[p * 8] = pk;
  }
  for (int i = tid; i < 2 * 16 * 136; i += 512) ((ushort*)hbuf)[i] = 0;

  // Persistent B fragments: coalesced 16B loads from bpk.
  short8 B[4][5];
#pragma unroll
  for (int g = 0; g < 4; ++g)
#pragma unroll
    for (int kf = 0; kf < 5; ++kf)
      B[g][kf] = *(const short8*)&bpk[((((w * 4 + g) * 5 + kf) * 64) + l) * 8];

  f32x4 c4 = {0.f, 0.f, 0.f, 0.f};
  float hreg[4];
  const int lq    = l >> 4;
  const int krow0 = lq * 8;
  const int srow0 = lq * 4;                // sample row base (C layout)
  const int col_d = w * 16 + (l & 15);     // this lane's d col

  __syncthreads();

  for (int t = 0; t < T; ++t) {
    const ushort* hb = hbuf[t & 1];
    short8 A[5];
#pragma unroll
    for (int kf = 0; kf < 4; ++kf)
      A[kf] = *(const short8*)(hb + (l & 15) * 136 + kf * 32 + krow0);
    A[4] = *(const short8*)(xfrag + (t * 64 + l) * 8);

    f32x4 acc[4];
#pragma unroll
    for (int g = 0; g < 4; ++g) {
      acc[g] = (f32x4){0.f, 0.f, 0.f, 0.f};
#pragma unroll
      for (int kf = 0; kf < 5; ++kf)
        acc[g] = __builtin_amdgcn_mfma_f32_16x16x32_bf16(A[kf], B[g][kf], acc[g], 0, 0, 0);
    }

    ushort* hw = hbuf[(t + 1) & 1];
#pragma unroll
    for (int r = 0; r < 4; ++r) {
      const float i_ = sigm(acc[0][r]);
      const float f_ = sigm(acc[1][r]);
      const float g_ = tanh_(acc[2][r]);
      const float o_ = sigm(acc[3][r]);
      c4[r]   = f_ * c4[r] + i_ * g_;
      hreg[r] = o_ * tanh_(c4[r]);
      hw[(srow0 + r) * 136 + col_d] = f2bf(hreg[r]);
    }
    __syncthreads();
  }

#pragma unroll
  for (int r = 0; r < 4; ++r) {
    feats[(n0 + srow0 + r + 1) * D + col_d] = hreg[r];
    fb16 [(n0 + srow0 + r + 1) * D + col_d] = f2bf(hreg[r]);
  }
}

// ---------------------------------------------------------------------------
// Kernel 2: projections, data-parallel. One block per feats row m.
// ---------------------------------------------------------------------------
__global__ __launch_bounds__(128) void proj_kernel(
    const float* __restrict__ feats, const float* __restrict__ wt,
    float* __restrict__ cur_term, float* __restrict__ nbr_proj,
    float* __restrict__ curwc)
{
  const int m = blockIdx.x;      // 0..1024
  const int j = threadIdx.x;     // 0..127
  __shared__ float frow[128];
  frow[j] = feats[m * D + j];
  __syncthreads();

  float acc = 0.0f;
#pragma unroll 8
  for (int d = 0; d < 128; ++d)
    acc = fmaf(frow[d], wt[d * 128 + j], acc);

  if (j < 59) nbr_proj[m * R + j] = acc;
  else if (m >= 1) {
    if (j < 118)       cur_term[(m - 1) * R + (j - 59)] = acc;
    else if (j == 118) curwc[m - 1] = acc;
  }
}

// ---------------------------------------------------------------------------
// Kernel 3: fused attention (r9 exact — best measured).
// ---------------------------------------------------------------------------
__device__ __forceinline__ void store_out(void* out, int i, float v, int outf32) {
  if (outf32) ((float*)out)[i] = v;
  else        ((__hip_bfloat16*)out)[i] = __float2bfloat16(v);
}

__global__ __launch_bounds__(256) void attn_kernel(
    const float* __restrict__ feats, const ushort* __restrict__ fb16,
    const int* __restrict__ neighbors,
    const float* __restrict__ W_state, const float* __restrict__ b_state,
    const float* __restrict__ W_relattn, const float* __restrict__ b_relattn,
    const float* __restrict__ W_pred, const float* __restrict__ b_pred,
    const float* __restrict__ cur_term, const float* __restrict__ nbr_proj,
    const float* __restrict__ curwc, const int* __restrict__ flagp,
    void* __restrict__ out)
{
  const int n   = blockIdx.x;
  const int tid = threadIdx.x;

  __shared__ ushort rr[R * 136];      // rel_reps bf16, 16B-aligned rows
  __shared__ int    idx_lds[R * NK];
  __shared__ float  w_lds[NK * 60];   // transposed [k][r]
  __shared__ float  s2part[16 * 68];  // D1 partial dots [d8][r], bank-defused
  __shared__ float  wn_lds[D];
  __shared__ float  ct_lds[R];
  __shared__ float  rt_lds[R];
  __shared__ float  s2_lds[R];
  __shared__ float  aw_lds[R];
  __shared__ float  upd_lds[D];
  __shared__ int    sflag;

  // A: constants + neighbor indices
  if (tid == 0) sflag = flagp[0];
  if (tid < R) {
    ct_lds[tid] = cur_term[n * R + tid];
    rt_lds[tid] = W_state[tid * WSTRIDE + 2 * D + tid] + b_state[tid];
  }
  if (tid >= 128 && tid < 256) wn_lds[tid - 128] = W_relattn[D + (tid - 128)];
  for (int i = tid; i < R * NK; i += 256) {
    const int r = i >> 4, k = i & 15;
    idx_lds[i] = neighbors[(r * N + n) * NK + k];
  }
  __syncthreads();
  const int outf32 = sflag;

  // B1: scores -> w_lds[k][r] (relu'd)
  for (int i = tid; i < R * NK; i += 256) {
    const int r = i >> 4, k = i & 15;
    float s = ct_lds[r] + nbr_proj[idx_lds[i] * R + r] + rt_lds[r];
    w_lds[k * 60 + r] = fmaxf(s, 0.0f);
  }
  __syncthreads();

  // B2: softmax over K per r (conflict-free columns)
  if (tid < R) {
    float mx = 0.0f;
#pragma unroll
    for (int k = 0; k < NK; ++k) mx = fmaxf(mx, w_lds[k * 60 + tid]);
    float sum = 0.0f;
    float e[NK];
#pragma unroll
    for (int k = 0; k < NK; ++k) {
      e[k] = __expf(w_lds[k * 60 + tid] - mx);
      sum += e[k];
    }
    const float inv = __builtin_amdgcn_rcpf(sum);
#pragma unroll
    for (int k = 0; k < NK; ++k) w_lds[k * 60 + tid] = e[k] * inv;
  }
  __syncthreads();

  // C: bf16 gather, fp32 accumulate; fold D1 partial dot; bf16 rr store.
  {
    const int d8 = tid & 15;        // 8-elem chunk of d
    const int rp = tid >> 4;        // 16 parallel r slots
    for (int r = rp; r < R; r += 16) {
      float acc[8];
#pragma unroll
      for (int j = 0; j < 8; ++j) acc[j] = 0.0f;
#pragma unroll
      for (int k = 0; k < NK; ++k) {
        const int m = idx_lds[r * NK + k];
        const uint4 v = *(const uint4*)&fb16[m * D + d8 * 8];
        const float wv = w_lds[k * 60 + r];
        acc[0] = fmaf(wv, __uint_as_float(v.x << 16),          acc[0]);
        acc[1] = fmaf(wv, __uint_as_float(v.x & 0xffff0000u),  acc[1]);
        acc[2] = fmaf(wv, __uint_as_float(v.y << 16),          acc[2]);
        acc[3] = fmaf(wv, __uint_as_float(v.y & 0xffff0000u),  acc[3]);
        acc[4] = fmaf(wv, __uint_as_float(v.z << 16),          acc[4]);
        acc[5] = fmaf(wv, __uint_as_float(v.z & 0xffff0000u),  acc[5]);
        acc[6] = fmaf(wv, __uint_as_float(v.w << 16),          acc[6]);
        acc[7] = fmaf(wv, __uint_as_float(v.w & 0xffff0000u),  acc[7]);
      }
      short8 pk;
#pragma unroll
      for (int j = 0; j < 8; ++j) pk[j] = (short)f2bf(acc[j]);
      *(short8*)&rr[r * 136 + d8 * 8] = pk;
      float p = 0.0f;
#pragma unroll
      for (int j = 0; j < 8; ++j) p = fmaf(acc[j], wn_lds[d8 * 8 + j], p);
      s2part[d8 * 68 + r] = p;
    }
  }
  __syncthreads();

  // D1: s2[r] = relu(curwc + sum of partials + wr[r] + b) — no shuffles
  if (tid < R) {
    float dot = 0.0f;
#pragma unroll
    for (int q = 0; q < 16; ++q) dot += s2part[q * 68 + tid];
    float v = curwc[n] + dot + W_relattn[2 * D + tid] + b_relattn[0];
    s2_lds[tid] = fmaxf(v, 0.0f);
  }
  __syncthreads();

  // D2: softmax over r (wave 0)
  if (tid < 64) {
    float v = (tid < R) ? s2_lds[tid] : -1e30f;
    float mx = v;
    for (int off = 32; off; off >>= 1) mx = fmaxf(mx, __shfl_xor(mx, off));
    float e = (tid < R) ? __expf(v - mx) : 0.0f;
    float sum = e;
    for (int off = 32; off; off >>= 1) sum += __shfl_xor(sum, off);
    if (tid < R) aw_lds[tid] = e / sum;
  }
  __syncthreads();

  // E: rel_agg + updated (rr bf16 unpack)
  if (tid < D) {
    float agg = 0.0f;
    for (int r = 0; r < R; ++r) agg = fmaf(aw_lds[r], bf2f(rr[r * 136 + tid]), agg);
    const float upd = feats[(n + 1) * D + tid] + agg;
    store_out(out, 2 * 3 * N + n * D + tid, upd, outf32);
    upd_lds[tid] = upd;
  }
  __syncthreads();

  // F: logits + prediction softmax (wave 0)
  if (tid < 64) {
    float p[3];
#pragma unroll
    for (int j = 0; j < 3; ++j) {
      float v = upd_lds[tid] * W_pred[tid * 3 + j] +
                upd_lds[tid + 64] * W_pred[(tid + 64) * 3 + j];
      for (int off = 32; off; off >>= 1) v += __shfl_xor(v, off);
      p[j] = v + b_pred[j];
    }
    if (tid == 0) {
      const float mx = fmaxf(p[0], fmaxf(p[1], p[2]));
      const float e0 = __expf(p[0] - mx), e1 = __expf(p[1] - mx), e2 = __expf(p[2] - mx);
      const float s = e0 + e1 + e2;
      store_out(out, n * 3 + 0, p[0], outf32);
      store_out(out, n * 3 + 1, p[1], outf32);
      store_out(out, n * 3 + 2, p[2], outf32);
      store_out(out, 3 * N + n * 3 + 0, e0 / s, outf32);
      store_out(out, 3 * N + n * 3 + 1, e1 / s, outf32);
      store_out(out, 3 * N + n * 3 + 2, e2 / s, outf32);
    }
  }
}

// ---------------------------------------------------------------------------
extern "C" void kernel_launch(void* const* d_in, const int* in_sizes, int n_in,
                              void* d_out, int out_size, void* d_ws, size_t ws_size,
                              hipStream_t stream)
{
  const int* neighbors = (const int*)d_in[1];
  float* ws = (float*)d_ws;

  CvtA ca;
  {
    constexpr int SS[6] = {18585, 59, 315, 1, 384, 3};
    int off = 0;
    for (int i = 0; i < 6; ++i) { ca.small[i] = d_in[5 + i]; ca.soff[i] = off; off += SS[i]; }
    ca.soff[6] = off;   // 19347
    ca.win  = d_in[0];
    ca.wk   = d_in[2];
    ca.wr   = d_in[3];
    ca.bias = d_in[4];
  }

  float*  csm      = ws;                         // 19360 (19347 + pad)
  float*  wtpack   = csm + 19360;                // 16384
  float*  feats    = wtpack + 16384;             // 131200
  float*  cur_term = feats + 131200;             // 60416
  float*  nbr_proj = cur_term + 60416;           // 60480
  float*  curwc    = nbr_proj + 60480;           // 1024
  int*    flagp    = (int*)(curwc + 1024);       // 16 floats pad
  ushort* bpk      = (ushort*)(curwc + 1040);    // 81920 ushort
  ushort* fb16     = bpk + 81920;                // 131200 ushort

  const float* c_Wstate = csm;
  const float* c_bstate = csm + 18585;
  const float* c_Wrel   = csm + 18644;
  const float* c_brel   = csm + 18959;
  const float* c_Wpred  = csm + 18960;
  const float* c_bpred  = csm + 19344;

  convert_kernel<<<256, 256, 0, stream>>>(ca, csm, wtpack, bpk, flagp);
  lstm_kernel<<<N / 16, 512, 0, stream>>>(bpk, d_in[0], flagp, feats, fb16);
  proj_kernel<<<N + 1, 128, 0, stream>>>(feats, wtpack, cur_term, nbr_proj, curwc);
  attn_kernel<<<N, 256, 0, stream>>>(feats, fb16, neighbors, c_Wstate, c_bstate, c_Wrel,
                                     c_brel, c_Wpred, c_bpred,
                                     cur_term, nbr_proj, curwc, flagp, d_out);
}